// Round 8
// baseline (239.195 us; speedup 1.0000x reference)
//
#include <hip/hip_runtime.h>
#include <hip/hip_bf16.h>

// Problem constants: B=4, S=4096, D=2048, K=4
// out[b,s,d] = bias[d] + sum_k w[d,k] * x[b, s-3+k, d]   (zero-pad s<0)
//
// R7 (resubmit — GPUAcquisitionTimeout, never benched): copy-shaped software
// pipeline. Each thread owns one d4 column and walks 32 s-rows in chunks of 4
// with register double-buffering:
//   issue 4 loads of chunk c+1  ->  compute+store chunk c  (loads in flight)
// Steady interleave of loads/stores (like the 6.3 TB/s copy ubench) instead
// of all-load / all-store convoys. Rolling 3-reg carry: halo ampl 35/32.

typedef float vfloat4 __attribute__((ext_vector_type(4)));

namespace {
constexpr int B = 4;
constexpr int S = 4096;
constexpr int D = 2048;
constexpr int D4 = D / 4;       // 512
constexpr int CH = 4;           // rows per chunk
constexpr int NCH = 8;          // chunks per strip
constexpr int STRIP = CH * NCH; // 32 rows per block
constexpr int BLOCK = 256;
}

__global__ __launch_bounds__(BLOCK) void causal_dwconv1d_k4(
    const vfloat4* __restrict__ x,      // [B*S*D4]
    const vfloat4* __restrict__ w4,     // [D]
    const vfloat4* __restrict__ bias4,  // [D4]
    vfloat4* __restrict__ out)          // [B*S*D4]
{
    const int d4 = blockIdx.x * BLOCK + threadIdx.x;   // 0..D4-1
    const int s0 = blockIdx.y * STRIP;
    const int b  = blockIdx.z;

    const vfloat4* xb = x   + (size_t)b * S * D4 + d4;
    vfloat4*       ob = out + (size_t)b * S * D4 + d4;

    const vfloat4 zero = (vfloat4)(0.f);

    const vfloat4 wa = w4[d4 * 4 + 0];
    const vfloat4 wb = w4[d4 * 4 + 1];
    const vfloat4 wc = w4[d4 * 4 + 2];
    const vfloat4 wd = w4[d4 * 4 + 3];
    const vfloat4 bv = bias4[d4];

    // Rolling carry (x[s-3], x[s-2], x[s-1]); s0==0 is the only guarded case.
    vfloat4 xm3, xm2, xm1;
    if (s0 >= 3) {
        xm3 = xb[(size_t)(s0 - 3) * D4];
        xm2 = xb[(size_t)(s0 - 2) * D4];
        xm1 = xb[(size_t)(s0 - 1) * D4];
    } else {
        xm3 = zero; xm2 = zero; xm1 = zero;   // s0 == 0
    }

    auto row = [&](const vfloat4 xc, int s) {
        vfloat4 o;
        o.x = bv.x + wa.x * xm3.x + wa.y * xm2.x + wa.z * xm1.x + wa.w * xc.x;
        o.y = bv.y + wb.x * xm3.y + wb.y * xm2.y + wb.z * xm1.y + wb.w * xc.y;
        o.z = bv.z + wc.x * xm3.z + wc.y * xm2.z + wc.z * xm1.z + wc.w * xc.z;
        o.w = bv.w + wd.x * xm3.w + wd.y * xm2.w + wd.z * xm1.w + wd.w * xc.w;
        ob[(size_t)s * D4] = o;
        xm3 = xm2; xm2 = xm1; xm1 = xc;
    };

    // Prologue: load chunk 0.
    vfloat4 c0 = xb[(size_t)(s0 + 0) * D4];
    vfloat4 c1 = xb[(size_t)(s0 + 1) * D4];
    vfloat4 c2 = xb[(size_t)(s0 + 2) * D4];
    vfloat4 c3 = xb[(size_t)(s0 + 3) * D4];

    for (int c = 0; c < NCH - 1; ++c) {
        const int sn = s0 + (c + 1) * CH;
        // Issue next chunk's loads (in flight during compute+stores below).
        const vfloat4 n0 = xb[(size_t)(sn + 0) * D4];
        const vfloat4 n1 = xb[(size_t)(sn + 1) * D4];
        const vfloat4 n2 = xb[(size_t)(sn + 2) * D4];
        const vfloat4 n3 = xb[(size_t)(sn + 3) * D4];
        const int sc = s0 + c * CH;
        row(c0, sc + 0);
        row(c1, sc + 1);
        row(c2, sc + 2);
        row(c3, sc + 3);
        c0 = n0; c1 = n1; c2 = n2; c3 = n3;
    }
    // Epilogue: last chunk.
    const int sc = s0 + (NCH - 1) * CH;
    row(c0, sc + 0);
    row(c1, sc + 1);
    row(c2, sc + 2);
    row(c3, sc + 3);
}

extern "C" void kernel_launch(void* const* d_in, const int* in_sizes, int n_in,
                              void* d_out, int out_size, void* d_ws, size_t ws_size,
                              hipStream_t stream) {
    const vfloat4* x     = (const vfloat4*)d_in[0];
    const vfloat4* w4    = (const vfloat4*)d_in[1];
    const vfloat4* bias4 = (const vfloat4*)d_in[2];
    vfloat4* out         = (vfloat4*)d_out;

    dim3 grid(D4 / BLOCK, S / STRIP, B);   // (2, 128, 4) = 1024 blocks
    dim3 block(BLOCK);
    causal_dwconv1d_k4<<<grid, block, 0, stream>>>(x, w4, bias4, out);
}